// Round 1
// baseline (95.978 us; speedup 1.0000x reference)
//
#include <hip/hip_runtime.h>

// N-body all-pairs gravitational force, N=8192, fp32.
// forces[i] = sum_j m_j * (p_j - p_i) / (|p_j - p_i|^2 + eps^2)^1.5
//
// Compute-bound: 67.1M pairs x ~13 VALU ops; inputs fit in L1/L2.
// 2D grid (N/256, JSPLIT): each block does 256 i's x (N/JSPLIT) j's,
// atomicAdd partial forces into d_out (zeroed via hipMemsetAsync first).

constexpr int   NBODY = 8192;
constexpr int   BLOCK = 256;
constexpr int   JSPLIT = 8;                    // 32 x 8 = 256 blocks -> all CUs
constexpr float SOFT2 = 0.01f * 0.01f;

__global__ __launch_bounds__(BLOCK) void nbody_forces(
    const float* __restrict__ pos,    // [N,3]
    const float* __restrict__ mass,   // [N]
    float*       __restrict__ out)    // [N,3], pre-zeroed
{
    const int tid = threadIdx.x;
    const int i   = blockIdx.x * BLOCK + tid;
    const int jPer = NBODY / JSPLIT;           // 1024
    const int j0  = blockIdx.y * jPer;

    const float xi = pos[3 * i + 0];
    const float yi = pos[3 * i + 1];
    const float zi = pos[3 * i + 2];

    float fx = 0.f, fy = 0.f, fz = 0.f;

    __shared__ float4 sh[BLOCK];               // xyz + mass per j

    for (int jt = j0; jt < j0 + jPer; jt += BLOCK) {
        const int j = jt + tid;
        sh[tid] = make_float4(pos[3 * j + 0], pos[3 * j + 1], pos[3 * j + 2], mass[j]);
        __syncthreads();

        #pragma unroll 8
        for (int k = 0; k < BLOCK; ++k) {
            const float4 p = sh[k];            // wave-uniform -> LDS broadcast
            const float dx = p.x - xi;
            const float dy = p.y - yi;
            const float dz = p.z - zi;
            const float d2 = fmaf(dx, dx, fmaf(dy, dy, fmaf(dz, dz, SOFT2)));
            const float inv  = rsqrtf(d2);     // v_rsq_f32
            const float inv3 = inv * inv * inv;
            const float s    = p.w * inv3;     // G = 1
            fx = fmaf(s, dx, fx);
            fy = fmaf(s, dy, fy);
            fz = fmaf(s, dz, fz);
            // j == i term: diff = 0 -> contribution 0, matches reference.
        }
        __syncthreads();
    }

    atomicAdd(&out[3 * i + 0], fx);
    atomicAdd(&out[3 * i + 1], fy);
    atomicAdd(&out[3 * i + 2], fz);
}

extern "C" void kernel_launch(void* const* d_in, const int* in_sizes, int n_in,
                              void* d_out, int out_size, void* d_ws, size_t ws_size,
                              hipStream_t stream) {
    const float* pos  = (const float*)d_in[0];
    const float* mass = (const float*)d_in[1];
    float* out = (float*)d_out;

    hipMemsetAsync(out, 0, (size_t)out_size * sizeof(float), stream);

    dim3 grid(NBODY / BLOCK, JSPLIT);
    nbody_forces<<<grid, BLOCK, 0, stream>>>(pos, mass, out);
}

// Round 2
// 86.909 us; speedup vs baseline: 1.1044x; 1.1044x over previous
//
#include <hip/hip_runtime.h>

// N-body all-pairs gravitational force, N=8192, fp32.
// forces[i] = sum_j m_j * (p_j - p_i) / (|p_j - p_i|^2 + eps^2)^1.5
//
// Round-2: occupancy was the bottleneck (9.8%, VALUBusy 58%).
// JSPLIT 8 -> 32: 1024 blocks = 16 waves/CU = 4 waves/SIMD.
// Inner loop unrolled with 4 independent accumulator triples for ILP.

constexpr int   NBODY = 8192;
constexpr int   BLOCK = 256;
constexpr int   JSPLIT = 32;                   // 32 x 32 = 1024 blocks
constexpr float SOFT2 = 0.01f * 0.01f;

__global__ __launch_bounds__(BLOCK) void nbody_forces(
    const float* __restrict__ pos,    // [N,3]
    const float* __restrict__ mass,   // [N]
    float*       __restrict__ out)    // [N,3], pre-zeroed
{
    const int tid = threadIdx.x;
    const int i   = blockIdx.x * BLOCK + tid;
    const int jPer = NBODY / JSPLIT;           // 256
    const int j0  = blockIdx.y * jPer;

    const float xi = pos[3 * i + 0];
    const float yi = pos[3 * i + 1];
    const float zi = pos[3 * i + 2];

    // 4 independent accumulator triples -> 12 independent FMA chains.
    float fx0 = 0.f, fy0 = 0.f, fz0 = 0.f;
    float fx1 = 0.f, fy1 = 0.f, fz1 = 0.f;
    float fx2 = 0.f, fy2 = 0.f, fz2 = 0.f;
    float fx3 = 0.f, fy3 = 0.f, fz3 = 0.f;

    __shared__ float4 sh[BLOCK];               // xyz + mass per j

    for (int jt = j0; jt < j0 + jPer; jt += BLOCK) {
        const int j = jt + tid;
        sh[tid] = make_float4(pos[3 * j + 0], pos[3 * j + 1], pos[3 * j + 2], mass[j]);
        __syncthreads();

        #pragma unroll
        for (int k = 0; k < BLOCK; k += 4) {
            {
                const float4 p = sh[k + 0];    // wave-uniform -> LDS broadcast
                const float dx = p.x - xi, dy = p.y - yi, dz = p.z - zi;
                const float d2 = fmaf(dx, dx, fmaf(dy, dy, fmaf(dz, dz, SOFT2)));
                const float inv  = rsqrtf(d2);
                const float s    = p.w * inv * inv * inv;
                fx0 = fmaf(s, dx, fx0); fy0 = fmaf(s, dy, fy0); fz0 = fmaf(s, dz, fz0);
            }
            {
                const float4 p = sh[k + 1];
                const float dx = p.x - xi, dy = p.y - yi, dz = p.z - zi;
                const float d2 = fmaf(dx, dx, fmaf(dy, dy, fmaf(dz, dz, SOFT2)));
                const float inv  = rsqrtf(d2);
                const float s    = p.w * inv * inv * inv;
                fx1 = fmaf(s, dx, fx1); fy1 = fmaf(s, dy, fy1); fz1 = fmaf(s, dz, fz1);
            }
            {
                const float4 p = sh[k + 2];
                const float dx = p.x - xi, dy = p.y - yi, dz = p.z - zi;
                const float d2 = fmaf(dx, dx, fmaf(dy, dy, fmaf(dz, dz, SOFT2)));
                const float inv  = rsqrtf(d2);
                const float s    = p.w * inv * inv * inv;
                fx2 = fmaf(s, dx, fx2); fy2 = fmaf(s, dy, fy2); fz2 = fmaf(s, dz, fz2);
            }
            {
                const float4 p = sh[k + 3];
                const float dx = p.x - xi, dy = p.y - yi, dz = p.z - zi;
                const float d2 = fmaf(dx, dx, fmaf(dy, dy, fmaf(dz, dz, SOFT2)));
                const float inv  = rsqrtf(d2);
                const float s    = p.w * inv * inv * inv;
                fx3 = fmaf(s, dx, fx3); fy3 = fmaf(s, dy, fy3); fz3 = fmaf(s, dz, fz3);
            }
        }
        __syncthreads();
    }

    const float fx = (fx0 + fx1) + (fx2 + fx3);
    const float fy = (fy0 + fy1) + (fy2 + fy3);
    const float fz = (fz0 + fz1) + (fz2 + fz3);

    atomicAdd(&out[3 * i + 0], fx);
    atomicAdd(&out[3 * i + 1], fy);
    atomicAdd(&out[3 * i + 2], fz);
}

extern "C" void kernel_launch(void* const* d_in, const int* in_sizes, int n_in,
                              void* d_out, int out_size, void* d_ws, size_t ws_size,
                              hipStream_t stream) {
    const float* pos  = (const float*)d_in[0];
    const float* mass = (const float*)d_in[1];
    float* out = (float*)d_out;

    hipMemsetAsync(out, 0, (size_t)out_size * sizeof(float), stream);

    dim3 grid(NBODY / BLOCK, JSPLIT);
    nbody_forces<<<grid, BLOCK, 0, stream>>>(pos, mass, out);
}

// Round 3
// 86.175 us; speedup vs baseline: 1.1138x; 1.0085x over previous
//
#include <hip/hip_runtime.h>

// N-body all-pairs gravitational force, N=8192, fp32.
//
// Round-3: no LDS, no barriers, no atomics.
//  - pack kernel: d_ws <- float4{x,y,z,m} per body (contiguous, 16B aligned)
//  - main kernel: j-loop reads packed[j] at wave-UNIFORM address -> scalar
//    (SGPR) loads on the SMEM pipe; 13 VALU ops/pair on the vector pipe.
//    grid (32, 64) = 2048 blocks = 8 waves/SIMD for latency hiding.
//    Partial forces stored (plain, deterministic) to d_ws.
//  - reduce kernel: out[e] = sum over 64 splits.

constexpr int   NBODY  = 8192;
constexpr int   BLOCK  = 256;
constexpr int   JSPLIT = 64;                   // 2048 blocks -> 8 waves/SIMD
constexpr int   JPER   = NBODY / JSPLIT;       // 128
constexpr float SOFT2  = 0.01f * 0.01f;
constexpr int   OUTE   = NBODY * 3;            // 24576 output elements

__global__ __launch_bounds__(256) void pack_kernel(
    const float* __restrict__ pos, const float* __restrict__ mass,
    float4* __restrict__ packed)
{
    const int j = blockIdx.x * blockDim.x + threadIdx.x;
    packed[j] = make_float4(pos[3 * j + 0], pos[3 * j + 1], pos[3 * j + 2], mass[j]);
}

__global__ __launch_bounds__(BLOCK, 8) void nbody_forces(
    const float4* __restrict__ packed,   // [N] {x,y,z,m}
    float*        __restrict__ part)     // [JSPLIT][N*3] partials
{
    const int tid = threadIdx.x;
    const int i   = blockIdx.x * BLOCK + tid;
    const int j0  = blockIdx.y * JPER;

    const float4 pi = packed[i];
    const float xi = pi.x, yi = pi.y, zi = pi.z;

    float fx = 0.f, fy = 0.f, fz = 0.f;

    #pragma unroll 8
    for (int j = j0; j < j0 + JPER; ++j) {
        const float4 p = packed[j];        // wave-uniform addr -> s_load
        const float dx = p.x - xi;
        const float dy = p.y - yi;
        const float dz = p.z - zi;
        const float d2 = fmaf(dx, dx, fmaf(dy, dy, fmaf(dz, dz, SOFT2)));
        const float inv  = __builtin_amdgcn_rsqf(d2);   // v_rsq_f32
        const float s    = p.w * inv * inv * inv;       // G = 1
        fx = fmaf(s, dx, fx);
        fy = fmaf(s, dy, fy);
        fz = fmaf(s, dz, fz);
        // j == i: diff = 0 -> contribution 0, matches reference.
    }

    float* dst = part + (size_t)blockIdx.y * OUTE;
    dst[3 * i + 0] = fx;
    dst[3 * i + 1] = fy;
    dst[3 * i + 2] = fz;
}

__global__ __launch_bounds__(256) void reduce_kernel(
    const float* __restrict__ part,      // [JSPLIT][OUTE]
    float*       __restrict__ out)       // [OUTE]
{
    const int e = blockIdx.x * blockDim.x + threadIdx.x;   // 0..OUTE-1
    float s = 0.f;
    #pragma unroll 8
    for (int k = 0; k < JSPLIT; ++k)
        s += part[(size_t)k * OUTE + e];
    out[e] = s;
}

extern "C" void kernel_launch(void* const* d_in, const int* in_sizes, int n_in,
                              void* d_out, int out_size, void* d_ws, size_t ws_size,
                              hipStream_t stream) {
    const float* pos  = (const float*)d_in[0];
    const float* mass = (const float*)d_in[1];
    float* out = (float*)d_out;

    // d_ws layout: [0, 128KB) packed float4; [128KB, +6.3MB) partials.
    float4* packed = (float4*)d_ws;
    float*  part   = (float*)((char*)d_ws + (size_t)NBODY * sizeof(float4));

    pack_kernel<<<NBODY / 256, 256, 0, stream>>>(pos, mass, packed);

    dim3 grid(NBODY / BLOCK, JSPLIT);
    nbody_forces<<<grid, BLOCK, 0, stream>>>(packed, part);

    reduce_kernel<<<OUTE / 256, 256, 0, stream>>>(part, out);
}

// Round 4
// 82.052 us; speedup vs baseline: 1.1697x; 1.0502x over previous
//
#include <hip/hip_runtime.h>

// N-body all-pairs gravitational force, N=8192, fp32.
//
// Round-4: LDS-broadcast j-tiles (round-1 structure, measured 0 bank
// conflicts) + high occupancy + i-register-blocking.
//  - IBLK=2 i-bodies per thread: halves ds_read/loop overhead per pair,
//    doubles independent FMA/rsq chains (ILP).
//  - grid (16,64) = 1024 blocks = 4 waves/SIMD (TLP).
//  - jPer = 128 = one LDS tile staged once; ONE barrier per block.
//  - __builtin_amdgcn_rsqf: bare v_rsq_f32, no IEEE fixup sequence.
//  - plain partial stores + tree reduce; no atomics, no memset.

constexpr int   NBODY   = 8192;
constexpr int   BLOCK   = 256;
constexpr int   IBLK    = 2;
constexpr int   IBODIES = BLOCK * IBLK;        // 512 i's per block
constexpr int   JSPLIT  = 64;
constexpr int   JPER    = NBODY / JSPLIT;      // 128 j's per block
constexpr float SOFT2   = 0.01f * 0.01f;
constexpr int   OUTE    = NBODY * 3;           // 24576

__global__ __launch_bounds__(256) void pack_kernel(
    const float* __restrict__ pos, const float* __restrict__ mass,
    float4* __restrict__ packed)
{
    const int j = blockIdx.x * blockDim.x + threadIdx.x;
    packed[j] = make_float4(pos[3 * j + 0], pos[3 * j + 1], pos[3 * j + 2], mass[j]);
}

__global__ __launch_bounds__(BLOCK, 4) void nbody_forces(
    const float4* __restrict__ packed,   // [N] {x,y,z,m}
    float*        __restrict__ part)     // [JSPLIT][N*3] partials
{
    const int tid = threadIdx.x;
    const int ia  = blockIdx.x * IBODIES + tid;       // first i-body
    const int ib  = ia + BLOCK;                        // second i-body
    const int j0  = blockIdx.y * JPER;

    __shared__ float4 sh[JPER];
    if (tid < JPER) sh[tid] = packed[j0 + tid];

    const float4 pa = packed[ia];
    const float4 pb = packed[ib];
    __syncthreads();

    float fax = 0.f, fay = 0.f, faz = 0.f;
    float fbx = 0.f, fby = 0.f, fbz = 0.f;

    #pragma unroll 8
    for (int k = 0; k < JPER; ++k) {
        const float4 p = sh[k];            // uniform addr -> HW broadcast
        // pair (ia, j)
        const float dxa = p.x - pa.x;
        const float dya = p.y - pa.y;
        const float dza = p.z - pa.z;
        const float d2a = fmaf(dxa, dxa, fmaf(dya, dya, fmaf(dza, dza, SOFT2)));
        const float ira = __builtin_amdgcn_rsqf(d2a);
        const float sa  = p.w * ira * ira * ira;
        fax = fmaf(sa, dxa, fax);
        fay = fmaf(sa, dya, fay);
        faz = fmaf(sa, dza, faz);
        // pair (ib, j) — independent chain
        const float dxb = p.x - pb.x;
        const float dyb = p.y - pb.y;
        const float dzb = p.z - pb.z;
        const float d2b = fmaf(dxb, dxb, fmaf(dyb, dyb, fmaf(dzb, dzb, SOFT2)));
        const float irb = __builtin_amdgcn_rsqf(d2b);
        const float sb  = p.w * irb * irb * irb;
        fbx = fmaf(sb, dxb, fbx);
        fby = fmaf(sb, dyb, fby);
        fbz = fmaf(sb, dzb, fbz);
        // j == i: diff = 0 -> contribution 0, matches reference.
    }

    float* dst = part + (size_t)blockIdx.y * OUTE;
    dst[3 * ia + 0] = fax;
    dst[3 * ia + 1] = fay;
    dst[3 * ia + 2] = faz;
    dst[3 * ib + 0] = fbx;
    dst[3 * ib + 1] = fby;
    dst[3 * ib + 2] = fbz;
}

__global__ __launch_bounds__(256) void reduce_kernel(
    const float* __restrict__ part,      // [JSPLIT][OUTE]
    float*       __restrict__ out)       // [OUTE]
{
    const int e = blockIdx.x * blockDim.x + threadIdx.x;
    float s = 0.f;
    #pragma unroll 8
    for (int k = 0; k < JSPLIT; ++k)
        s += part[(size_t)k * OUTE + e];
    out[e] = s;
}

extern "C" void kernel_launch(void* const* d_in, const int* in_sizes, int n_in,
                              void* d_out, int out_size, void* d_ws, size_t ws_size,
                              hipStream_t stream) {
    const float* pos  = (const float*)d_in[0];
    const float* mass = (const float*)d_in[1];
    float* out = (float*)d_out;

    float4* packed = (float4*)d_ws;
    float*  part   = (float*)((char*)d_ws + (size_t)NBODY * sizeof(float4));

    pack_kernel<<<NBODY / 256, 256, 0, stream>>>(pos, mass, packed);

    dim3 grid(NBODY / IBODIES, JSPLIT);   // (16, 64)
    nbody_forces<<<grid, BLOCK, 0, stream>>>(packed, part);

    reduce_kernel<<<OUTE / 256, 256, 0, stream>>>(part, out);
}